// Round 1
// baseline (754.564 us; speedup 1.0000x reference)
//
#include <hip/hip_runtime.h>
#include <hip/hip_bf16.h>

// Problem constants
#define T_TOK 4096
#define D_DIM 1024
#define E_EXP 8
#define F_DIM 2816
#define K_TOP 2
#define TK (T_TOK * K_TOP)          // 8192 (token,k) pairs
#define BM 128
#define MT_MAX (TK / BM + E_EXP)    // 72 worst-case M-tiles
#define NT1 (F_DIM / 128)           // 22
#define NT2 (D_DIM / 128)           // 8
#define CAP (TK + E_EXP * BM)       // 9216 padded slot capacity

typedef __attribute__((ext_vector_type(4))) float f32x4;
typedef __attribute__((ext_vector_type(8))) short bf16x8;

// ws layout (all offsets 256B-aligned by construction)
#define OFF_XBF   ((size_t)0)
#define OFF_GUPBF (OFF_XBF   + (size_t)T_TOK * D_DIM * 2)            // 8,388,608
#define OFF_DWNBF (OFF_GUPBF + (size_t)E_EXP * 2 * F_DIM * D_DIM * 2)
#define OFF_ACT   (OFF_DWNBF + (size_t)E_EXP * D_DIM * F_DIM * 2)
#define OFF_PAIRS (OFF_ACT   + (size_t)CAP * F_DIM * 2)
#define OFF_TOK   (OFF_PAIRS + (size_t)CAP * D_DIM * 4)
#define OFF_WSL   (OFF_TOK   + (size_t)CAP * 4)
#define OFF_SLOT  (OFF_WSL   + (size_t)CAP * 4)
#define OFF_TILES (OFF_SLOT  + (size_t)TK * 4)

__device__ __forceinline__ unsigned short f2bf(float f) {
    unsigned u = __float_as_uint(f);
    unsigned r = u + 0x7FFFu + ((u >> 16) & 1u);   // RNE
    return (unsigned short)(r >> 16);
}

#define GLOAD16(g, l)                                                          \
    __builtin_amdgcn_global_load_lds(                                          \
        (const __attribute__((address_space(1))) void*)(g),                    \
        (__attribute__((address_space(3))) void*)(l), 16, 0, 0)

// ---------------- fp32 -> bf16 convert ----------------
__global__ void cvt_kernel(const float4* __restrict__ src,
                           ushort4* __restrict__ dst, int n4) {
    int i = blockIdx.x * blockDim.x + threadIdx.x;
    int stride = gridDim.x * blockDim.x;
    for (; i < n4; i += stride) {
        float4 v = src[i];
        ushort4 o;
        o.x = f2bf(v.x); o.y = f2bf(v.y); o.z = f2bf(v.z); o.w = f2bf(v.w);
        dst[i] = o;
    }
}

// ---------------- routing: bucket (t,k) pairs by expert ----------------
__global__ void route_kernel(const int* __restrict__ ids,
                             const float* __restrict__ wts,
                             int* __restrict__ tok, float* __restrict__ wsl,
                             int* __restrict__ slot_of, int* __restrict__ tiles) {
    __shared__ int s_cnt[E_EXP], s_base[E_EXP], s_off[E_EXP];
    int tid = threadIdx.x;
    if (tid < E_EXP) { s_cnt[tid] = 0; s_off[tid] = 0; }
    __syncthreads();
    for (int i = tid; i < TK; i += 256) atomicAdd(&s_cnt[ids[i]], 1);
    __syncthreads();
    if (tid == 0) {
        int run = 0, nt = 0;
        for (int e = 0; e < E_EXP; ++e) {
            s_base[e] = run;
            int c = s_cnt[e];
            int mt = (c + BM - 1) / BM;
            for (int m = 0; m < mt; ++m) {
                tiles[2 * nt] = e; tiles[2 * nt + 1] = run + m * BM; ++nt;
            }
            run += mt * BM;
        }
        for (; nt < MT_MAX; ++nt) { tiles[2 * nt] = -1; tiles[2 * nt + 1] = 0; }
    }
    __syncthreads();
    // default-fill all slots (pads: token 0, weight 0)
    for (int i = tid; i < CAP; i += 256) { tok[i] = 0; wsl[i] = 0.f; }
    __syncthreads();
    for (int i = tid; i < TK; i += 256) {
        int e = ids[i];
        int pos = atomicAdd(&s_off[e], 1);
        int s = s_base[e] + pos;
        tok[s] = i >> 1;        // token id (i = t*K + k)
        wsl[s] = wts[i];
        slot_of[i] = s;
    }
}

// ---------------- GEMM1: h = x @ gate_up^T, act = silu(g)*u ----------------
// Tile 128x128, BK=64, 4 waves (2x2), 16x16x32 bf16 MFMA, dual accumulators.
__global__ __launch_bounds__(256) void gemm1_kernel(
    const unsigned short* __restrict__ xb,    // [T][D] bf16
    const unsigned short* __restrict__ gup,   // [E][2F][D] bf16
    unsigned short* __restrict__ act,         // [CAP][F] bf16
    const int* __restrict__ tok,
    const int* __restrict__ tiles) {
    int mt = blockIdx.x;
    int e = tiles[2 * mt];
    if (e < 0) return;
    int m0 = tiles[2 * mt + 1];
    int j0 = blockIdx.y * 128;

    __shared__ unsigned short sA[128 * 64];
    __shared__ unsigned short sG[128 * 64];
    __shared__ unsigned short sU[128 * 64];

    int tid = threadIdx.x;
    int lane = tid & 63, wid = tid >> 6;
    int wm = wid >> 1, wn = wid & 1;
    int srow = tid >> 3;             // 0..31, staging row per iter
    int sbyte = (tid & 7) * 16;      // byte offset within 128B row

    const unsigned short* gup_e = gup + (size_t)e * (2 * (size_t)F_DIM) * D_DIM;

    int trow[4];
#pragma unroll
    for (int it = 0; it < 4; ++it) trow[it] = tok[m0 + srow + 32 * it];

    f32x4 accg[4][4], accu[4][4];
#pragma unroll
    for (int i = 0; i < 4; ++i)
#pragma unroll
        for (int j = 0; j < 4; ++j) {
            accg[i][j] = {0.f, 0.f, 0.f, 0.f};
            accu[i][j] = {0.f, 0.f, 0.f, 0.f};
        }

    for (int k0 = 0; k0 < D_DIM; k0 += 64) {
#pragma unroll
        for (int it = 0; it < 4; ++it) {
            int r = srow + 32 * it;
            GLOAD16((const char*)xb + ((size_t)trow[it] * D_DIM + k0) * 2 + sbyte,
                    (char*)sA + r * 128 + sbyte);
        }
#pragma unroll
        for (int it = 0; it < 4; ++it) {
            int r = srow + 32 * it;
            GLOAD16((const char*)gup_e + ((size_t)(j0 + r) * D_DIM + k0) * 2 + sbyte,
                    (char*)sG + r * 128 + sbyte);
        }
#pragma unroll
        for (int it = 0; it < 4; ++it) {
            int r = srow + 32 * it;
            GLOAD16((const char*)gup_e + ((size_t)(F_DIM + j0 + r) * D_DIM + k0) * 2 + sbyte,
                    (char*)sU + r * 128 + sbyte);
        }
        __syncthreads();

#pragma unroll
        for (int kk = 0; kk < 64; kk += 32) {
            bf16x8 af[4], gf[4], uf[4];
            int kb = kk + (lane >> 4) * 8;
#pragma unroll
            for (int m = 0; m < 4; ++m)
                af[m] = *(const bf16x8*)&sA[(wm * 64 + m * 16 + (lane & 15)) * 64 + kb];
#pragma unroll
            for (int n = 0; n < 4; ++n) {
                gf[n] = *(const bf16x8*)&sG[(wn * 64 + n * 16 + (lane & 15)) * 64 + kb];
                uf[n] = *(const bf16x8*)&sU[(wn * 64 + n * 16 + (lane & 15)) * 64 + kb];
            }
#pragma unroll
            for (int m = 0; m < 4; ++m)
#pragma unroll
                for (int n = 0; n < 4; ++n) {
                    accg[m][n] = __builtin_amdgcn_mfma_f32_16x16x32_bf16(
                        af[m], gf[n], accg[m][n], 0, 0, 0);
                    accu[m][n] = __builtin_amdgcn_mfma_f32_16x16x32_bf16(
                        af[m], uf[n], accu[m][n], 0, 0, 0);
                }
        }
        __syncthreads();
    }

    // epilogue: silu(g)*u -> bf16
#pragma unroll
    for (int m = 0; m < 4; ++m)
#pragma unroll
        for (int n = 0; n < 4; ++n)
#pragma unroll
            for (int r = 0; r < 4; ++r) {
                int row = wm * 64 + m * 16 + (lane >> 4) * 4 + r;
                int col = wn * 64 + n * 16 + (lane & 15);
                float g = accg[m][n][r], u = accu[m][n][r];
                float a = g / (1.f + __expf(-g)) * u;
                act[(size_t)(m0 + row) * F_DIM + j0 + col] = f2bf(a);
            }
}

// ---------------- GEMM2: pairs = (act @ down^T) * w ----------------
__global__ __launch_bounds__(256) void gemm2_kernel(
    const unsigned short* __restrict__ act,   // [CAP][F] bf16
    const unsigned short* __restrict__ dwn,   // [E][D][F] bf16
    float* __restrict__ pairs,                // [CAP][D] f32
    const float* __restrict__ wsl,
    const int* __restrict__ tiles) {
    int mt = blockIdx.x;
    int e = tiles[2 * mt];
    if (e < 0) return;
    int m0 = tiles[2 * mt + 1];
    int d0 = blockIdx.y * 128;

    __shared__ unsigned short sA[128 * 64];
    __shared__ unsigned short sB[128 * 64];

    int tid = threadIdx.x;
    int lane = tid & 63, wid = tid >> 6;
    int wm = wid >> 1, wn = wid & 1;
    int srow = tid >> 3;
    int sbyte = (tid & 7) * 16;

    const unsigned short* dwn_e = dwn + (size_t)e * D_DIM * F_DIM;

    f32x4 acc[4][4];
#pragma unroll
    for (int i = 0; i < 4; ++i)
#pragma unroll
        for (int j = 0; j < 4; ++j) acc[i][j] = {0.f, 0.f, 0.f, 0.f};

    for (int k0 = 0; k0 < F_DIM; k0 += 64) {
#pragma unroll
        for (int it = 0; it < 4; ++it) {
            int r = srow + 32 * it;
            GLOAD16((const char*)act + ((size_t)(m0 + r) * F_DIM + k0) * 2 + sbyte,
                    (char*)sA + r * 128 + sbyte);
            GLOAD16((const char*)dwn_e + ((size_t)(d0 + r) * F_DIM + k0) * 2 + sbyte,
                    (char*)sB + r * 128 + sbyte);
        }
        __syncthreads();

#pragma unroll
        for (int kk = 0; kk < 64; kk += 32) {
            bf16x8 af[4], bfr[4];
            int kb = kk + (lane >> 4) * 8;
#pragma unroll
            for (int m = 0; m < 4; ++m)
                af[m] = *(const bf16x8*)&sA[(wm * 64 + m * 16 + (lane & 15)) * 64 + kb];
#pragma unroll
            for (int n = 0; n < 4; ++n)
                bfr[n] = *(const bf16x8*)&sB[(wn * 64 + n * 16 + (lane & 15)) * 64 + kb];
#pragma unroll
            for (int m = 0; m < 4; ++m)
#pragma unroll
                for (int n = 0; n < 4; ++n)
                    acc[m][n] = __builtin_amdgcn_mfma_f32_16x16x32_bf16(
                        af[m], bfr[n], acc[m][n], 0, 0, 0);
        }
        __syncthreads();
    }

#pragma unroll
    for (int m = 0; m < 4; ++m)
#pragma unroll
        for (int n = 0; n < 4; ++n)
#pragma unroll
            for (int r = 0; r < 4; ++r) {
                int row = wm * 64 + m * 16 + (lane >> 4) * 4 + r;
                int col = wn * 64 + n * 16 + (lane & 15);
                float w = wsl[m0 + row];
                pairs[(size_t)(m0 + row) * D_DIM + d0 + col] = acc[m][n][r] * w;
            }
}

// ---------------- combine: out[t] = pairs[slot(t,0)] + pairs[slot(t,1)] ----
__global__ void combine_kernel(const float4* __restrict__ pairs,
                               const int* __restrict__ slot_of,
                               float4* __restrict__ out) {
    const int DC = D_DIM / 4;   // 256
    int i = blockIdx.x * blockDim.x + threadIdx.x;
    int stride = gridDim.x * blockDim.x;
    for (; i < T_TOK * DC; i += stride) {
        int t = i / DC;
        int c = i - t * DC;
        int s0 = slot_of[2 * t], s1 = slot_of[2 * t + 1];
        float4 a = pairs[(size_t)s0 * DC + c];
        float4 b = pairs[(size_t)s1 * DC + c];
        float4 o;
        o.x = a.x + b.x; o.y = a.y + b.y; o.z = a.z + b.z; o.w = a.w + b.w;
        out[i] = o;
    }
}

extern "C" void kernel_launch(void* const* d_in, const int* in_sizes, int n_in,
                              void* d_out, int out_size, void* d_ws, size_t ws_size,
                              hipStream_t stream) {
    const float* x   = (const float*)d_in[0];
    const float* gup = (const float*)d_in[1];
    const float* dwn = (const float*)d_in[2];
    const float* tw  = (const float*)d_in[3];
    const int*   tid = (const int*)d_in[4];
    float* out = (float*)d_out;

    char* ws = (char*)d_ws;
    unsigned short* xbf   = (unsigned short*)(ws + OFF_XBF);
    unsigned short* gupbf = (unsigned short*)(ws + OFF_GUPBF);
    unsigned short* dwnbf = (unsigned short*)(ws + OFF_DWNBF);
    unsigned short* act   = (unsigned short*)(ws + OFF_ACT);
    float*          pairs = (float*)(ws + OFF_PAIRS);
    int*            tok   = (int*)(ws + OFF_TOK);
    float*          wsl   = (float*)(ws + OFF_WSL);
    int*            slot  = (int*)(ws + OFF_SLOT);
    int*            tiles = (int*)(ws + OFF_TILES);

    cvt_kernel<<<1024, 256, 0, stream>>>((const float4*)x, (ushort4*)xbf,
                                         T_TOK * D_DIM / 4);
    cvt_kernel<<<2048, 256, 0, stream>>>((const float4*)gup, (ushort4*)gupbf,
                                         E_EXP * 2 * F_DIM * D_DIM / 4);
    cvt_kernel<<<2048, 256, 0, stream>>>((const float4*)dwn, (ushort4*)dwnbf,
                                         E_EXP * D_DIM * F_DIM / 4);
    route_kernel<<<1, 256, 0, stream>>>(tid, tw, tok, wsl, slot, tiles);
    gemm1_kernel<<<dim3(MT_MAX, NT1), 256, 0, stream>>>(xbf, gupbf, act, tok, tiles);
    gemm2_kernel<<<dim3(MT_MAX, NT2), 256, 0, stream>>>(act, dwnbf, pairs, wsl, tiles);
    combine_kernel<<<1024, 256, 0, stream>>>((const float4*)pairs, slot,
                                             (float4*)out);
}

// Round 2
// 702.220 us; speedup vs baseline: 1.0745x; 1.0745x over previous
//
#include <hip/hip_runtime.h>
#include <hip/hip_bf16.h>

// Problem constants
#define T_TOK 4096
#define D_DIM 1024
#define E_EXP 8
#define F_DIM 2816
#define K_TOP 2
#define TK (T_TOK * K_TOP)          // 8192 (token,k) pairs
#define BM 128
#define MT_MAX (TK / BM + E_EXP)    // 72 worst-case M-tiles
#define NT1 (F_DIM / 128)           // 22
#define NT2 (D_DIM / 128)           // 8
#define CAP (TK + E_EXP * BM)       // 9216 padded slot capacity

typedef __attribute__((ext_vector_type(4))) float f32x4;
typedef __attribute__((ext_vector_type(8))) short bf16x8;

// ws layout (all offsets 256B-aligned by construction)
#define OFF_XBF   ((size_t)0)
#define OFF_GUPBF (OFF_XBF   + (size_t)T_TOK * D_DIM * 2)
#define OFF_DWNBF (OFF_GUPBF + (size_t)E_EXP * 2 * F_DIM * D_DIM * 2)
#define OFF_ACT   (OFF_DWNBF + (size_t)E_EXP * D_DIM * F_DIM * 2)
#define OFF_PAIRS (OFF_ACT   + (size_t)CAP * F_DIM * 2)
#define OFF_TOK   (OFF_PAIRS + (size_t)CAP * D_DIM * 4)
#define OFF_WSL   (OFF_TOK   + (size_t)CAP * 4)
#define OFF_SLOT  (OFF_WSL   + (size_t)CAP * 4)
#define OFF_TILES (OFF_SLOT  + (size_t)TK * 4)

__device__ __forceinline__ unsigned short f2bf(float f) {
    unsigned u = __float_as_uint(f);
    unsigned r = u + 0x7FFFu + ((u >> 16) & 1u);   // RNE
    return (unsigned short)(r >> 16);
}

#define GLOAD16(g, l)                                                          \
    __builtin_amdgcn_global_load_lds(                                          \
        (const __attribute__((address_space(1))) void*)(g),                    \
        (__attribute__((address_space(3))) void*)(l), 16, 0, 0)

// ---------------- fp32 -> bf16 convert ----------------
__global__ void cvt_kernel(const float4* __restrict__ src,
                           ushort4* __restrict__ dst, int n4) {
    int i = blockIdx.x * blockDim.x + threadIdx.x;
    int stride = gridDim.x * blockDim.x;
    for (; i < n4; i += stride) {
        float4 v = src[i];
        ushort4 o;
        o.x = f2bf(v.x); o.y = f2bf(v.y); o.z = f2bf(v.z); o.w = f2bf(v.w);
        dst[i] = o;
    }
}

// ---------------- routing: bucket (t,k) pairs by expert ----------------
__global__ void route_kernel(const int* __restrict__ ids,
                             const float* __restrict__ wts,
                             int* __restrict__ tok, float* __restrict__ wsl,
                             int* __restrict__ slot_of, int* __restrict__ tiles) {
    __shared__ int s_cnt[E_EXP], s_base[E_EXP], s_off[E_EXP];
    int tid = threadIdx.x;
    if (tid < E_EXP) { s_cnt[tid] = 0; s_off[tid] = 0; }
    __syncthreads();
    for (int i = tid; i < TK; i += 256) atomicAdd(&s_cnt[ids[i]], 1);
    __syncthreads();
    if (tid == 0) {
        int run = 0, nt = 0;
        for (int e = 0; e < E_EXP; ++e) {
            s_base[e] = run;
            int c = s_cnt[e];
            int mt = (c + BM - 1) / BM;
            for (int m = 0; m < mt; ++m) {
                tiles[2 * nt] = e; tiles[2 * nt + 1] = run + m * BM; ++nt;
            }
            run += mt * BM;
        }
        for (; nt < MT_MAX; ++nt) { tiles[2 * nt] = -1; tiles[2 * nt + 1] = 0; }
    }
    __syncthreads();
    // default-fill all slots (pads: token 0, weight 0)
    for (int i = tid; i < CAP; i += 256) { tok[i] = 0; wsl[i] = 0.f; }
    __syncthreads();
    for (int i = tid; i < TK; i += 256) {
        int e = ids[i];
        int pos = atomicAdd(&s_off[e], 1);
        int s = s_base[e] + pos;
        tok[s] = i >> 1;        // token id (i = t*K + k)
        wsl[s] = wts[i];
        slot_of[i] = s;
    }
}

// ---------------- GEMM1: h = x @ gate_up^T, act = silu(g)*u ----------------
// Tile 128x128, BK=64, 4 waves (2x2), 16x16x32 bf16 MFMA, dual accumulators.
// T2: st-16x32-style XOR swizzle (byte ^= (row&7)<<4). LDS dest stays linear
// (global_load_lds requirement); the global SOURCE address is pre-swizzled,
// and ds_read addresses apply the same XOR (both-sides rule, m173/m201).
// T1: 1-D grid with XCD-chunked bijective swizzle (nwg % 8 == 0).
__global__ __launch_bounds__(256) void gemm1_kernel(
    const unsigned short* __restrict__ xb,    // [T][D] bf16
    const unsigned short* __restrict__ gup,   // [E][2F][D] bf16
    unsigned short* __restrict__ act,         // [CAP][F] bf16
    const int* __restrict__ tok,
    const int* __restrict__ tiles) {
    const int nwg = MT_MAX * NT1;             // 1584, %8==0
    int bid = blockIdx.x;
    int swz = (bid & 7) * (nwg >> 3) + (bid >> 3);
    int mt = swz % MT_MAX;                    // mt-fast within XCD chunk:
    int nt = swz / MT_MAX;                    // consecutive same-e blocks share
    int e = tiles[2 * mt];                    // the (e,j0) weight tile in L2
    if (e < 0) return;
    int m0 = tiles[2 * mt + 1];
    int j0 = nt * 128;

    __shared__ unsigned short sA[128 * 64];
    __shared__ unsigned short sG[128 * 64];
    __shared__ unsigned short sU[128 * 64];

    int tid = threadIdx.x;
    int lane = tid & 63, wid = tid >> 6;
    int wm = wid >> 1, wn = wid & 1;
    int srow = tid >> 3;             // 0..31, staging row per iter
    int sbyte = (tid & 7) * 16;      // linear byte offset within 128B LDS row
    int sbx = sbyte ^ ((srow & 7) << 4);   // pre-swizzled global byte offset

    const unsigned short* gup_e = gup + (size_t)e * (2 * (size_t)F_DIM) * D_DIM;

    int trow[4];
#pragma unroll
    for (int it = 0; it < 4; ++it) trow[it] = tok[m0 + srow + 32 * it];

    f32x4 accg[4][4], accu[4][4];
#pragma unroll
    for (int i = 0; i < 4; ++i)
#pragma unroll
        for (int j = 0; j < 4; ++j) {
            accg[i][j] = {0.f, 0.f, 0.f, 0.f};
            accu[i][j] = {0.f, 0.f, 0.f, 0.f};
        }

    int rswz = (lane & 7) << 4;      // read-side XOR, uniform over fragments

    for (int k0 = 0; k0 < D_DIM; k0 += 64) {
#pragma unroll
        for (int it = 0; it < 4; ++it) {
            int r = srow + 32 * it;
            GLOAD16((const char*)xb + ((size_t)trow[it] * D_DIM + k0) * 2 + sbx,
                    (char*)sA + r * 128 + sbyte);
        }
#pragma unroll
        for (int it = 0; it < 4; ++it) {
            int r = srow + 32 * it;
            GLOAD16((const char*)gup_e + ((size_t)(j0 + r) * D_DIM + k0) * 2 + sbx,
                    (char*)sG + r * 128 + sbyte);
        }
#pragma unroll
        for (int it = 0; it < 4; ++it) {
            int r = srow + 32 * it;
            GLOAD16((const char*)gup_e + ((size_t)(F_DIM + j0 + r) * D_DIM + k0) * 2 + sbx,
                    (char*)sU + r * 128 + sbyte);
        }
        __syncthreads();

#pragma unroll
        for (int kk = 0; kk < 64; kk += 32) {
            bf16x8 af[4], gf[4], uf[4];
            int cbyte = (((lane >> 4) * 16) + kk * 2) ^ rswz;  // swizzled col byte
#pragma unroll
            for (int m = 0; m < 4; ++m) {
                int row = wm * 64 + m * 16 + (lane & 15);
                af[m] = *(const bf16x8*)((const char*)sA + row * 128 + cbyte);
            }
#pragma unroll
            for (int n = 0; n < 4; ++n) {
                int row = wn * 64 + n * 16 + (lane & 15);
                gf[n] = *(const bf16x8*)((const char*)sG + row * 128 + cbyte);
                uf[n] = *(const bf16x8*)((const char*)sU + row * 128 + cbyte);
            }
#pragma unroll
            for (int m = 0; m < 4; ++m)
#pragma unroll
                for (int n = 0; n < 4; ++n) {
                    accg[m][n] = __builtin_amdgcn_mfma_f32_16x16x32_bf16(
                        af[m], gf[n], accg[m][n], 0, 0, 0);
                    accu[m][n] = __builtin_amdgcn_mfma_f32_16x16x32_bf16(
                        af[m], uf[n], accu[m][n], 0, 0, 0);
                }
        }
        __syncthreads();
    }

    // epilogue: silu(g)*u -> bf16
#pragma unroll
    for (int m = 0; m < 4; ++m)
#pragma unroll
        for (int n = 0; n < 4; ++n)
#pragma unroll
            for (int r = 0; r < 4; ++r) {
                int row = wm * 64 + m * 16 + (lane >> 4) * 4 + r;
                int col = wn * 64 + n * 16 + (lane & 15);
                float g = accg[m][n][r], u = accu[m][n][r];
                float a = g / (1.f + __expf(-g)) * u;
                act[(size_t)(m0 + row) * F_DIM + j0 + col] = f2bf(a);
            }
}

// ---------------- GEMM2: pairs = (act @ down^T) * w ----------------
__global__ __launch_bounds__(256) void gemm2_kernel(
    const unsigned short* __restrict__ act,   // [CAP][F] bf16
    const unsigned short* __restrict__ dwn,   // [E][D][F] bf16
    float* __restrict__ pairs,                // [CAP][D] f32
    const float* __restrict__ wsl,
    const int* __restrict__ tiles) {
    const int nwg = MT_MAX * NT2;             // 576, %8==0
    int bid = blockIdx.x;
    int swz = (bid & 7) * (nwg >> 3) + (bid >> 3);
    int mt = swz % MT_MAX;
    int nt = swz / MT_MAX;
    int e = tiles[2 * mt];
    if (e < 0) return;
    int m0 = tiles[2 * mt + 1];
    int d0 = nt * 128;

    __shared__ unsigned short sA[128 * 64];
    __shared__ unsigned short sB[128 * 64];

    int tid = threadIdx.x;
    int lane = tid & 63, wid = tid >> 6;
    int wm = wid >> 1, wn = wid & 1;
    int srow = tid >> 3;
    int sbyte = (tid & 7) * 16;
    int sbx = sbyte ^ ((srow & 7) << 4);

    const unsigned short* dwn_e = dwn + (size_t)e * D_DIM * F_DIM;

    f32x4 acc[4][4];
#pragma unroll
    for (int i = 0; i < 4; ++i)
#pragma unroll
        for (int j = 0; j < 4; ++j) acc[i][j] = {0.f, 0.f, 0.f, 0.f};

    int rswz = (lane & 7) << 4;

    for (int k0 = 0; k0 < F_DIM; k0 += 64) {
#pragma unroll
        for (int it = 0; it < 4; ++it) {
            int r = srow + 32 * it;
            GLOAD16((const char*)act + ((size_t)(m0 + r) * F_DIM + k0) * 2 + sbx,
                    (char*)sA + r * 128 + sbyte);
            GLOAD16((const char*)dwn_e + ((size_t)(d0 + r) * F_DIM + k0) * 2 + sbx,
                    (char*)sB + r * 128 + sbyte);
        }
        __syncthreads();

#pragma unroll
        for (int kk = 0; kk < 64; kk += 32) {
            bf16x8 af[4], bfr[4];
            int cbyte = (((lane >> 4) * 16) + kk * 2) ^ rswz;
#pragma unroll
            for (int m = 0; m < 4; ++m) {
                int row = wm * 64 + m * 16 + (lane & 15);
                af[m] = *(const bf16x8*)((const char*)sA + row * 128 + cbyte);
            }
#pragma unroll
            for (int n = 0; n < 4; ++n) {
                int row = wn * 64 + n * 16 + (lane & 15);
                bfr[n] = *(const bf16x8*)((const char*)sB + row * 128 + cbyte);
            }
#pragma unroll
            for (int m = 0; m < 4; ++m)
#pragma unroll
                for (int n = 0; n < 4; ++n)
                    acc[m][n] = __builtin_amdgcn_mfma_f32_16x16x32_bf16(
                        af[m], bfr[n], acc[m][n], 0, 0, 0);
        }
        __syncthreads();
    }

#pragma unroll
    for (int m = 0; m < 4; ++m)
#pragma unroll
        for (int n = 0; n < 4; ++n)
#pragma unroll
            for (int r = 0; r < 4; ++r) {
                int row = wm * 64 + m * 16 + (lane >> 4) * 4 + r;
                int col = wn * 64 + n * 16 + (lane & 15);
                float w = wsl[m0 + row];
                pairs[(size_t)(m0 + row) * D_DIM + d0 + col] = acc[m][n][r] * w;
            }
}

// ---------------- combine: out[t] = pairs[slot(t,0)] + pairs[slot(t,1)] ----
__global__ void combine_kernel(const float4* __restrict__ pairs,
                               const int* __restrict__ slot_of,
                               float4* __restrict__ out) {
    const int DC = D_DIM / 4;   // 256
    int i = blockIdx.x * blockDim.x + threadIdx.x;
    int stride = gridDim.x * blockDim.x;
    for (; i < T_TOK * DC; i += stride) {
        int t = i / DC;
        int c = i - t * DC;
        int s0 = slot_of[2 * t], s1 = slot_of[2 * t + 1];
        float4 a = pairs[(size_t)s0 * DC + c];
        float4 b = pairs[(size_t)s1 * DC + c];
        float4 o;
        o.x = a.x + b.x; o.y = a.y + b.y; o.z = a.z + b.z; o.w = a.w + b.w;
        out[i] = o;
    }
}

extern "C" void kernel_launch(void* const* d_in, const int* in_sizes, int n_in,
                              void* d_out, int out_size, void* d_ws, size_t ws_size,
                              hipStream_t stream) {
    const float* x   = (const float*)d_in[0];
    const float* gup = (const float*)d_in[1];
    const float* dwn = (const float*)d_in[2];
    const float* tw  = (const float*)d_in[3];
    const int*   tid = (const int*)d_in[4];
    float* out = (float*)d_out;

    char* ws = (char*)d_ws;
    unsigned short* xbf   = (unsigned short*)(ws + OFF_XBF);
    unsigned short* gupbf = (unsigned short*)(ws + OFF_GUPBF);
    unsigned short* dwnbf = (unsigned short*)(ws + OFF_DWNBF);
    unsigned short* act   = (unsigned short*)(ws + OFF_ACT);
    float*          pairs = (float*)(ws + OFF_PAIRS);
    int*            tok   = (int*)(ws + OFF_TOK);
    float*          wsl   = (float*)(ws + OFF_WSL);
    int*            slot  = (int*)(ws + OFF_SLOT);
    int*            tiles = (int*)(ws + OFF_TILES);

    cvt_kernel<<<1024, 256, 0, stream>>>((const float4*)x, (ushort4*)xbf,
                                         T_TOK * D_DIM / 4);
    cvt_kernel<<<2048, 256, 0, stream>>>((const float4*)gup, (ushort4*)gupbf,
                                         E_EXP * 2 * F_DIM * D_DIM / 4);
    cvt_kernel<<<2048, 256, 0, stream>>>((const float4*)dwn, (ushort4*)dwnbf,
                                         E_EXP * D_DIM * F_DIM / 4);
    route_kernel<<<1, 256, 0, stream>>>(tid, tw, tok, wsl, slot, tiles);
    gemm1_kernel<<<MT_MAX * NT1, 256, 0, stream>>>(xbf, gupbf, act, tok, tiles);
    gemm2_kernel<<<MT_MAX * NT2, 256, 0, stream>>>(act, dwnbf, pairs, wsl, tiles);
    combine_kernel<<<1024, 256, 0, stream>>>((const float4*)pairs, slot,
                                             (float4*)out);
}